// Round 7
// baseline (379.282 us; speedup 1.0000x reference)
//
#include <hip/hip_runtime.h>
#include <hip/hip_bf16.h>

// QuanvolutionGraphQLClassifier — f32 in/out. SINGLE fused kernel.
// Circuit factorizes into wires {0,1} x {2,3}; each Pauli-Z expectation is a
// bilinear form e_d = wA . H_d . wB with w(a) = (cos^2 a/2, cos a/2 sin a/2,
// sin^2 a/2), H_d fixed 3x3 from q_params (numerics verified R4-R6, absmax 0.5).
//
// R6 lesson: the separate producer kernel (W2 fold) stayed ~40 us across three
// structural variants; fuse everything. Blocks 0..9 each build W2 row k
// (sample-0 meas -> LDS; per-thread adjacency column, division-free threshold;
// wave-uniform float4 W loads) and release a flag in ws. All 512 blocks
// (2 samples/wave, 8/block) build H in regs, measure their own samples
// (overlapping the writers), acquire-spin on the 10 flags, then dot vs W2 +
// butterfly reduce + log_softmax. Grid 512 <= half of guaranteed residency at
// launch_bounds(256,4) => writers always get scheduled; flags live in d_ws
// (re-poisoned 0xAA each replay, != MAGIC, so no init pass needed).

#define NP 196
#define MAGIC 0x13572468u

__device__ __forceinline__ float quad3(const float* H, const float* wa,
                                       const float* wb) {
  return wa[0] * (H[0] * wb[0] + H[1] * wb[1] + H[2] * wb[2]) +
         wa[1] * (H[3] * wb[0] + H[4] * wb[1] + H[5] * wb[2]) +
         wa[2] * (H[6] * wb[0] + H[7] * wb[1] + H[8] * wb[2]);
}

// Builds the full H[36] (A: 0..17, B: 18..35) — wave-uniform, all regs.
__device__ __forceinline__ void build_H_all(const float* __restrict__ qp,
                                            float* __restrict__ H) {
  float qc[6], qs[6];
#pragma unroll
  for (int i = 0; i < 6; ++i) __sincosf(0.5f * qp[i], &qs[i], &qc[i]);
#pragma unroll
  for (int sub = 0; sub < 2; ++sub) {
    float Mr[4][4] = {}, Mi[4][4] = {};
    if (sub == 0) {
      // U_A = RY(q4,w0) * CNOT01 * RY(q1,w1) * RX(q0,w0); index = 2*b0 + b1
      Mr[0][0] = Mr[1][1] = Mr[2][2] = Mr[3][3] = qc[0];  // RX(q0) on w0
      Mi[0][2] = Mi[2][0] = Mi[1][3] = Mi[3][1] = -qs[0];
#pragma unroll
      for (int j = 0; j < 4; ++j) {  // RY(q1) on w1: rows (0,1),(2,3)
        float a, b;
        a = Mr[0][j]; b = Mr[1][j]; Mr[0][j] = qc[1]*a - qs[1]*b; Mr[1][j] = qs[1]*a + qc[1]*b;
        a = Mi[0][j]; b = Mi[1][j]; Mi[0][j] = qc[1]*a - qs[1]*b; Mi[1][j] = qs[1]*a + qc[1]*b;
        a = Mr[2][j]; b = Mr[3][j]; Mr[2][j] = qc[1]*a - qs[1]*b; Mr[3][j] = qs[1]*a + qc[1]*b;
        a = Mi[2][j]; b = Mi[3][j]; Mi[2][j] = qc[1]*a - qs[1]*b; Mi[3][j] = qs[1]*a + qc[1]*b;
      }
#pragma unroll
      for (int j = 0; j < 4; ++j) {  // CNOT(0,1): swap rows 2,3
        float r = Mr[2][j]; Mr[2][j] = Mr[3][j]; Mr[3][j] = r;
        float q = Mi[2][j]; Mi[2][j] = Mi[3][j]; Mi[3][j] = q;
      }
#pragma unroll
      for (int j = 0; j < 4; ++j) {  // RY(q4) on w0: rows (0,2),(1,3)
        float a, b;
        a = Mr[0][j]; b = Mr[2][j]; Mr[0][j] = qc[4]*a - qs[4]*b; Mr[2][j] = qs[4]*a + qc[4]*b;
        a = Mi[0][j]; b = Mi[2][j]; Mi[0][j] = qc[4]*a - qs[4]*b; Mi[2][j] = qs[4]*a + qc[4]*b;
        a = Mr[1][j]; b = Mr[3][j]; Mr[1][j] = qc[4]*a - qs[4]*b; Mr[3][j] = qs[4]*a + qc[4]*b;
        a = Mi[1][j]; b = Mi[3][j]; Mi[1][j] = qc[4]*a - qs[4]*b; Mi[3][j] = qs[4]*a + qc[4]*b;
      }
    } else {
      // U_B = RZ(q5,w3) * CNOT23 * RX(q3,w3) * RZ(q2,w2); index = 2*b2 + b3
      Mr[0][0] = Mr[1][1] = Mr[2][2] = Mr[3][3] = qc[2];  // RZ(q2) on w2
      Mi[0][0] = Mi[1][1] = -qs[2]; Mi[2][2] = Mi[3][3] = qs[2];
#pragma unroll
      for (int j = 0; j < 4; ++j) {  // RX(q3) on w3: rows (0,1),(2,3)
        float ra, ia, rb, ib;
        ra = Mr[0][j]; ia = Mi[0][j]; rb = Mr[1][j]; ib = Mi[1][j];
        Mr[0][j] = qc[3]*ra + qs[3]*ib;  Mi[0][j] = qc[3]*ia - qs[3]*rb;
        Mr[1][j] = qc[3]*rb + qs[3]*ia;  Mi[1][j] = qc[3]*ib - qs[3]*ra;
        ra = Mr[2][j]; ia = Mi[2][j]; rb = Mr[3][j]; ib = Mi[3][j];
        Mr[2][j] = qc[3]*ra + qs[3]*ib;  Mi[2][j] = qc[3]*ia - qs[3]*rb;
        Mr[3][j] = qc[3]*rb + qs[3]*ia;  Mi[3][j] = qc[3]*ib - qs[3]*ra;
      }
#pragma unroll
      for (int j = 0; j < 4; ++j) {  // CNOT(2,3): swap rows 2,3
        float r = Mr[2][j]; Mr[2][j] = Mr[3][j]; Mr[3][j] = r;
        float q = Mi[2][j]; Mi[2][j] = Mi[3][j]; Mi[3][j] = q;
      }
#pragma unroll
      for (int r = 0; r < 4; ++r) {  // RZ(q5) on w3: rows 0,2 *(c5-is5); 1,3 *(c5+is5)
        float sg = (r & 1) ? 1.0f : -1.0f;
#pragma unroll
        for (int j = 0; j < 4; ++j) {
          float re = Mr[r][j], im = Mi[r][j];
          Mr[r][j] = qc[5] * re - sg * qs[5] * im;
          Mi[r][j] = qc[5] * im + sg * qs[5] * re;
        }
      }
    }
    // G_d[j][k] = sum_i sigma_i (Re U_ij Re U_ik + Im U_ij Im U_ik)
#pragma unroll
    for (int d = 0; d < 2; ++d) {
      float G[4][4];
#pragma unroll
      for (int j = 0; j < 4; ++j)
#pragma unroll
        for (int k = 0; k < 4; ++k) {
          float g = 0.0f;
#pragma unroll
          for (int i = 0; i < 4; ++i) {
            float sg = (d == 0) ? ((i < 2) ? 1.f : -1.f)
                                : (((i & 1) == 0) ? 1.f : -1.f);
            g += sg * (Mr[i][j] * Mr[i][k] + Mi[i][j] * Mi[i][k]);
          }
          G[j][k] = g;
        }
      float* Hd = H + sub * 18 + d * 9;
      Hd[0] = G[0][0];       Hd[1] = 2.f * G[0][1];               Hd[2] = G[1][1];
      Hd[3] = 2.f * G[0][2]; Hd[4] = 2.f * (G[0][3] + G[1][2]);   Hd[5] = 2.f * G[1][3];
      Hd[6] = G[2][2];       Hd[7] = 2.f * G[2][3];               Hd[8] = G[3][3];
    }
  }
}

// Pauli-Z expectations of patch p of image xb, via the H bilinear forms.
__device__ __forceinline__ void meas_patch(const float* __restrict__ xb, int p,
                                           const float* __restrict__ H,
                                           float* e) {
  int i = p / 14, j = p - 14 * i;
  float2 top = *(const float2*)(xb + 56 * i + 2 * j);
  float2 bot = *(const float2*)(xb + 56 * i + 28 + 2 * j);
  float c0, s0, c1, s1, c2, s2, c3, s3;
  __sincosf(0.5f * top.x, &s0, &c0);
  __sincosf(0.5f * top.y, &s1, &c1);
  __sincosf(0.5f * bot.x, &s2, &c2);
  __sincosf(0.5f * bot.y, &s3, &c3);
  float wA0[3] = {c0 * c0, c0 * s0, s0 * s0};
  float wA1[3] = {c1 * c1, c1 * s1, s1 * s1};
  float wB0[3] = {c2 * c2, c2 * s2, s2 * s2};
  float wB1[3] = {c3 * c3, c3 * s3, s3 * s3};
  e[0] = quad3(H, wA0, wA1);
  e[1] = quad3(H + 9, wA0, wA1);
  e[2] = quad3(H + 18, wB0, wB1);
  e[3] = quad3(H + 27, wB0, wB1);
}

__global__ __launch_bounds__(256, 4) void k_all(
    const float* __restrict__ x, const float* __restrict__ qp,
    const float* __restrict__ W, const float* __restrict__ bias,
    float* __restrict__ out, float* __restrict__ W2,
    unsigned int* __restrict__ flags, int Bsz) {
  __shared__ float4 vs4[NP];   // sample-0 measurements (writer blocks only)
  __shared__ float ns[NP];
  int t = threadIdx.x, wv = t >> 6, lane = t & 63;
  int bid = blockIdx.x;

  float H[36];
  build_H_all(qp, H);  // wave-uniform, registers only

  // ---- writer blocks 0..9: W2 row k = bid (grid is always >= 10 here) ----
  if (bid < 10) {
    if (wv == 0) {
#pragma unroll
      for (int r = 0; r < 4; ++r) {
        int p = lane + 64 * r;
        if (p < NP) {
          float e[4];
          meas_patch(x, p, H, e);
          vs4[p] = make_float4(e[0], e[1], e[2], e[3]);
          ns[p] = sqrtf(e[0]*e[0] + e[1]*e[1] + e[2]*e[2] + e[3]*e[3]);
        }
      }
    }
    __syncthreads();
    if (t < NP) {
      int m = t;
      float4 vm = vs4[m];
      float nm = ns[m];
      float a0 = 0.f, a1 = 0.f, a2 = 0.f, a3 = 0.f;
      const float* Wk = W + bid * 784;
      for (int n = 0; n < NP; ++n) {
        float4 vn = vs4[n];                 // LDS broadcast (uniform n)
        float dot = vm.x*vn.x + vm.y*vn.y + vm.z*vn.z + vm.w*vn.w;
        float D = nm * ns[n] + 1e-12f;      // > 0, so threshold div-free
        float w = (dot >= 0.9f * D) ? 1.0f : ((dot >= 0.5f * D) ? 0.5f : 0.0f);
        float4 wk = *(const float4*)(Wk + 4 * n);  // uniform -> scalar load
        a0 += w * wk.x; a1 += w * wk.y; a2 += w * wk.z; a3 += w * wk.w;
      }
      float* dst = W2 + bid * 784 + 4 * m;
      dst[0] = a0; dst[1] = a1; dst[2] = a2; dst[3] = a3;
    }
    __threadfence();      // make this thread's W2 stores agent-visible
    __syncthreads();      // all threads' stores fenced before the flag
    if (t == 0)
      __hip_atomic_store(&flags[bid], MAGIC, __ATOMIC_RELEASE,
                         __HIP_MEMORY_SCOPE_AGENT);
  }

  // ---- all blocks: measure own 2 samples per wave (overlaps writers) ----
  int b0 = bid * 8 + wv * 2;
  float ev[2][16];
#pragma unroll
  for (int s = 0; s < 2; ++s) {
    int b = b0 + s;
    if (b < Bsz) {
      const float* xb = x + (size_t)b * 784;
#pragma unroll
      for (int r = 0; r < 4; ++r) {
        int p = lane + 64 * r;
        if (p < NP) {
          float e[4];
          meas_patch(xb, p, H, e);
          ev[s][4*r+0] = e[0]; ev[s][4*r+1] = e[1];
          ev[s][4*r+2] = e[2]; ev[s][4*r+3] = e[3];
        }
      }
    }
  }

  // ---- spin until all 10 W2 rows are published ----
  if (lane == 0) {
#pragma unroll 1
    for (int i = 0; i < 10; ++i) {
      while (__hip_atomic_load(&flags[i], __ATOMIC_ACQUIRE,
                               __HIP_MEMORY_SCOPE_AGENT) != MAGIC)
        __builtin_amdgcn_s_sleep(8);
    }
  }
  __threadfence();  // order subsequent W2 loads after the acquire

  // ---- dot vs W2, butterfly reduce, log_softmax ----
  float bv[10];
#pragma unroll
  for (int k = 0; k < 10; ++k) bv[k] = bias[k];
#pragma unroll
  for (int s = 0; s < 2; ++s) {
    int b = b0 + s;
    if (b >= Bsz) continue;
    float acc[10];
#pragma unroll
    for (int k = 0; k < 10; ++k) acc[k] = 0.0f;
#pragma unroll
    for (int r = 0; r < 4; ++r) {
      int p = lane + 64 * r;
      if (p < NP) {
        float e0 = ev[s][4*r+0], e1 = ev[s][4*r+1];
        float e2 = ev[s][4*r+2], e3 = ev[s][4*r+3];
#pragma unroll
        for (int k = 0; k < 10; ++k) {
          float4 w = *(const float4*)(W2 + k * 784 + 4 * p);
          acc[k] += e0 * w.x + e1 * w.y + e2 * w.z + e3 * w.w;
        }
      }
    }
#pragma unroll
    for (int k = 0; k < 10; ++k)
#pragma unroll
      for (int off = 32; off; off >>= 1) acc[k] += __shfl_xor(acc[k], off);
    float lg[10], m = -1e30f;
#pragma unroll
    for (int k = 0; k < 10; ++k) { lg[k] = acc[k] + bv[k]; m = fmaxf(m, lg[k]); }
    float sm = 0.0f;
#pragma unroll
    for (int k = 0; k < 10; ++k) sm += __expf(lg[k] - m);
    float lse = m + __logf(sm);
    if (lane < 10) {
      float sel = lg[0];
#pragma unroll
      for (int k = 1; k < 10; ++k) sel = (lane == k) ? lg[k] : sel;
      out[(size_t)b * 10 + lane] = sel - lse;
    }
  }
}

extern "C" void kernel_launch(void* const* d_in, const int* in_sizes, int n_in,
                              void* d_out, int out_size, void* d_ws, size_t ws_size,
                              hipStream_t stream) {
  const float* x  = (const float*)d_in[0];  // (B,1,28,28) f32
  const float* qp = (const float*)d_in[1];  // (6,) f32
  const float* W  = (const float*)d_in[2];  // (10,784) f32
  const float* bi = (const float*)d_in[3];  // (10,) f32
  float* out = (float*)d_out;               // (B,10) f32

  int Bsz = in_sizes[0] / 784;              // 4096

  float* W2 = (float*)d_ws;                          // 7840 f32
  unsigned int* flags = (unsigned int*)(W2 + 7840);  // 10 u32 (0xAA.. != MAGIC)

  int grid = (Bsz + 7) / 8;                 // 512 blocks, 2 samples per wave
  k_all<<<grid, 256, 0, stream>>>(x, qp, W, bi, out, W2, flags, Bsz);
}

// Round 8
// 135.828 us; speedup vs baseline: 2.7924x; 2.7924x over previous
//
#include <hip/hip_runtime.h>
#include <hip/hip_bf16.h>

// QuanvolutionGraphQLClassifier — f32 in/out. ONE kernel, no producer stage,
// no inter-block sync (R7 lesson: forced-occupancy bounds => VGPR-64 spills,
// 9.5 MB scratch writes; R2-R6 lesson: any separate producer kernel stalls
// ~40 us at VALUBusy~1%).
//
// Math: circuit factorizes into wires {0,1} x {2,3}; Pauli-Z expectation is a
// bilinear form e_d = wA . H_d . wB, H_d fixed 3x3 from q_params (verified
// R4-R7, absmax 0.5). Adjacency applied PER SAMPLE:
//   agg[n] = sum_m adj(n,m) * meas[m],  logits[k] = sum_n agg[n].W[k,4n..] + b
// adj(n,m) from normalized sample-0 measurement vectors u (LDS), thresholds
// division-free. Block = 4 waves = 4 samples; 1024 independent blocks.

#define NP 196

__device__ __forceinline__ float quad3(const float* H, const float* wa,
                                       const float* wb) {
  return wa[0] * (H[0] * wb[0] + H[1] * wb[1] + H[2] * wb[2]) +
         wa[1] * (H[3] * wb[0] + H[4] * wb[1] + H[5] * wb[2]) +
         wa[2] * (H[6] * wb[0] + H[7] * wb[1] + H[8] * wb[2]);
}

// Builds the full H[36] (A: 0..17, B: 18..35) — wave-uniform, all regs.
__device__ __forceinline__ void build_H_all(const float* __restrict__ qp,
                                            float* __restrict__ H) {
  float qc[6], qs[6];
#pragma unroll
  for (int i = 0; i < 6; ++i) __sincosf(0.5f * qp[i], &qs[i], &qc[i]);
#pragma unroll
  for (int sub = 0; sub < 2; ++sub) {
    float Mr[4][4] = {}, Mi[4][4] = {};
    if (sub == 0) {
      // U_A = RY(q4,w0) * CNOT01 * RY(q1,w1) * RX(q0,w0); index = 2*b0 + b1
      Mr[0][0] = Mr[1][1] = Mr[2][2] = Mr[3][3] = qc[0];  // RX(q0) on w0
      Mi[0][2] = Mi[2][0] = Mi[1][3] = Mi[3][1] = -qs[0];
#pragma unroll
      for (int j = 0; j < 4; ++j) {  // RY(q1) on w1: rows (0,1),(2,3)
        float a, b;
        a = Mr[0][j]; b = Mr[1][j]; Mr[0][j] = qc[1]*a - qs[1]*b; Mr[1][j] = qs[1]*a + qc[1]*b;
        a = Mi[0][j]; b = Mi[1][j]; Mi[0][j] = qc[1]*a - qs[1]*b; Mi[1][j] = qs[1]*a + qc[1]*b;
        a = Mr[2][j]; b = Mr[3][j]; Mr[2][j] = qc[1]*a - qs[1]*b; Mr[3][j] = qs[1]*a + qc[1]*b;
        a = Mi[2][j]; b = Mi[3][j]; Mi[2][j] = qc[1]*a - qs[1]*b; Mi[3][j] = qs[1]*a + qc[1]*b;
      }
#pragma unroll
      for (int j = 0; j < 4; ++j) {  // CNOT(0,1): swap rows 2,3
        float r = Mr[2][j]; Mr[2][j] = Mr[3][j]; Mr[3][j] = r;
        float q = Mi[2][j]; Mi[2][j] = Mi[3][j]; Mi[3][j] = q;
      }
#pragma unroll
      for (int j = 0; j < 4; ++j) {  // RY(q4) on w0: rows (0,2),(1,3)
        float a, b;
        a = Mr[0][j]; b = Mr[2][j]; Mr[0][j] = qc[4]*a - qs[4]*b; Mr[2][j] = qs[4]*a + qc[4]*b;
        a = Mi[0][j]; b = Mi[2][j]; Mi[0][j] = qc[4]*a - qs[4]*b; Mi[2][j] = qs[4]*a + qc[4]*b;
        a = Mr[1][j]; b = Mr[3][j]; Mr[1][j] = qc[4]*a - qs[4]*b; Mr[3][j] = qs[4]*a + qc[4]*b;
        a = Mi[1][j]; b = Mi[3][j]; Mi[1][j] = qc[4]*a - qs[4]*b; Mi[3][j] = qs[4]*a + qc[4]*b;
      }
    } else {
      // U_B = RZ(q5,w3) * CNOT23 * RX(q3,w3) * RZ(q2,w2); index = 2*b2 + b3
      Mr[0][0] = Mr[1][1] = Mr[2][2] = Mr[3][3] = qc[2];  // RZ(q2) on w2
      Mi[0][0] = Mi[1][1] = -qs[2]; Mi[2][2] = Mi[3][3] = qs[2];
#pragma unroll
      for (int j = 0; j < 4; ++j) {  // RX(q3) on w3: rows (0,1),(2,3)
        float ra, ia, rb, ib;
        ra = Mr[0][j]; ia = Mi[0][j]; rb = Mr[1][j]; ib = Mi[1][j];
        Mr[0][j] = qc[3]*ra + qs[3]*ib;  Mi[0][j] = qc[3]*ia - qs[3]*rb;
        Mr[1][j] = qc[3]*rb + qs[3]*ia;  Mi[1][j] = qc[3]*ib - qs[3]*ra;
        ra = Mr[2][j]; ia = Mi[2][j]; rb = Mr[3][j]; ib = Mi[3][j];
        Mr[2][j] = qc[3]*ra + qs[3]*ib;  Mi[2][j] = qc[3]*ia - qs[3]*rb;
        Mr[3][j] = qc[3]*rb + qs[3]*ia;  Mi[3][j] = qc[3]*ib - qs[3]*ra;
      }
#pragma unroll
      for (int j = 0; j < 4; ++j) {  // CNOT(2,3): swap rows 2,3
        float r = Mr[2][j]; Mr[2][j] = Mr[3][j]; Mr[3][j] = r;
        float q = Mi[2][j]; Mi[2][j] = Mi[3][j]; Mi[3][j] = q;
      }
#pragma unroll
      for (int r = 0; r < 4; ++r) {  // RZ(q5) on w3: rows 0,2 *(c5-is5); 1,3 *(c5+is5)
        float sg = (r & 1) ? 1.0f : -1.0f;
#pragma unroll
        for (int j = 0; j < 4; ++j) {
          float re = Mr[r][j], im = Mi[r][j];
          Mr[r][j] = qc[5] * re - sg * qs[5] * im;
          Mi[r][j] = qc[5] * im + sg * qs[5] * re;
        }
      }
    }
    // G_d[j][k] = sum_i sigma_i (Re U_ij Re U_ik + Im U_ij Im U_ik)
#pragma unroll
    for (int d = 0; d < 2; ++d) {
      float G[4][4];
#pragma unroll
      for (int j = 0; j < 4; ++j)
#pragma unroll
        for (int k = 0; k < 4; ++k) {
          float g = 0.0f;
#pragma unroll
          for (int i = 0; i < 4; ++i) {
            float sg = (d == 0) ? ((i < 2) ? 1.f : -1.f)
                                : (((i & 1) == 0) ? 1.f : -1.f);
            g += sg * (Mr[i][j] * Mr[i][k] + Mi[i][j] * Mi[i][k]);
          }
          G[j][k] = g;
        }
      float* Hd = H + sub * 18 + d * 9;
      Hd[0] = G[0][0];       Hd[1] = 2.f * G[0][1];               Hd[2] = G[1][1];
      Hd[3] = 2.f * G[0][2]; Hd[4] = 2.f * (G[0][3] + G[1][2]);   Hd[5] = 2.f * G[1][3];
      Hd[6] = G[2][2];       Hd[7] = 2.f * G[2][3];               Hd[8] = G[3][3];
    }
  }
}

// Pauli-Z expectations of patch p of image xb, via the H bilinear forms.
__device__ __forceinline__ void meas_patch(const float* __restrict__ xb, int p,
                                           const float* __restrict__ H,
                                           float* e) {
  int i = p / 14, j = p - 14 * i;
  float2 top = *(const float2*)(xb + 56 * i + 2 * j);
  float2 bot = *(const float2*)(xb + 56 * i + 28 + 2 * j);
  float c0, s0, c1, s1, c2, s2, c3, s3;
  __sincosf(0.5f * top.x, &s0, &c0);
  __sincosf(0.5f * top.y, &s1, &c1);
  __sincosf(0.5f * bot.x, &s2, &c2);
  __sincosf(0.5f * bot.y, &s3, &c3);
  float wA0[3] = {c0 * c0, c0 * s0, s0 * s0};
  float wA1[3] = {c1 * c1, c1 * s1, s1 * s1};
  float wB0[3] = {c2 * c2, c2 * s2, s2 * s2};
  float wB1[3] = {c3 * c3, c3 * s3, s3 * s3};
  e[0] = quad3(H, wA0, wA1);
  e[1] = quad3(H + 9, wA0, wA1);
  e[2] = quad3(H + 18, wB0, wB1);
  e[3] = quad3(H + 27, wB0, wB1);
}

__global__ __launch_bounds__(256, 1) void k_fused(
    const float* __restrict__ x, const float* __restrict__ qp,
    const float* __restrict__ W, const float* __restrict__ bias,
    float* __restrict__ out, int Bsz) {
  __shared__ float4 us[NP];        // sample-0 measurements, normalized
  __shared__ float4 ms[4][NP];     // per-wave own-sample measurements
  int t = threadIdx.x, wv = t >> 6, lane = t & 63;
  int b = blockIdx.x * 4 + wv;

  float H[36];
  build_H_all(qp, H);  // wave-uniform, registers only

  // sample-0 measurements (threads 0..195), normalized for div-free threshold
  if (t < NP) {
    float e[4];
    meas_patch(x, t, H, e);
    float n = sqrtf(e[0]*e[0] + e[1]*e[1] + e[2]*e[2] + e[3]*e[3]) + 1e-12f;
    float rn = 1.0f / n;
    us[t] = make_float4(e[0]*rn, e[1]*rn, e[2]*rn, e[3]*rn);
  }
  // own-sample measurements
  bool alive = (b < Bsz);
  const float* xb = x + (size_t)(alive ? b : 0) * 784;
#pragma unroll
  for (int r = 0; r < 4; ++r) {
    int p = lane + 64 * r;
    if (p < NP) {
      float e[4];
      meas_patch(xb, p, H, e);
      ms[wv][p] = make_float4(e[0], e[1], e[2], e[3]);
    }
  }
  __syncthreads();

  // agg[n] = sum_m adj(n,m) * meas[m]; lane owns n = lane + 64r
  float4 un[4];
  float4 agg[4];
#pragma unroll
  for (int r = 0; r < 4; ++r) {
    int n = lane + 64 * r;
    un[r] = (n < NP) ? us[n] : make_float4(0, 0, 0, 0);
    agg[r] = make_float4(0, 0, 0, 0);
  }
  for (int m = 0; m < NP; ++m) {
    float4 um = us[m];        // uniform -> LDS broadcast
    float4 mm = ms[wv][m];
#pragma unroll
    for (int r = 0; r < 4; ++r) {
      float dot = un[r].x*um.x + un[r].y*um.y + un[r].z*um.z + un[r].w*um.w;
      float w = (dot >= 0.9f) ? 1.0f : ((dot >= 0.5f) ? 0.5f : 0.0f);
      agg[r].x += w * mm.x; agg[r].y += w * mm.y;
      agg[r].z += w * mm.z; agg[r].w += w * mm.w;
    }
  }

  // logits[k] = sum_n agg[n] . W[k, 4n..4n+3]
  float acc[10];
#pragma unroll
  for (int k = 0; k < 10; ++k) acc[k] = 0.0f;
#pragma unroll
  for (int r = 0; r < 4; ++r) {
    int n = lane + 64 * r;
    if (n < NP) {
#pragma unroll
      for (int k = 0; k < 10; ++k) {
        float4 w4 = *(const float4*)(W + k * 784 + 4 * n);
        acc[k] += agg[r].x * w4.x + agg[r].y * w4.y +
                  agg[r].z * w4.z + agg[r].w * w4.w;
      }
    }
  }
  // butterfly: every lane ends with all 10 totals
#pragma unroll
  for (int k = 0; k < 10; ++k)
#pragma unroll
    for (int off = 32; off; off >>= 1) acc[k] += __shfl_xor(acc[k], off);

  if (!alive) return;
  float lg[10], mx = -1e30f;
#pragma unroll
  for (int k = 0; k < 10; ++k) { lg[k] = acc[k] + bias[k]; mx = fmaxf(mx, lg[k]); }
  float sm = 0.0f;
#pragma unroll
  for (int k = 0; k < 10; ++k) sm += __expf(lg[k] - mx);
  float lse = mx + __logf(sm);
  if (lane < 10) {
    float sel = lg[0];
#pragma unroll
    for (int k = 1; k < 10; ++k) sel = (lane == k) ? lg[k] : sel;
    out[(size_t)b * 10 + lane] = sel - lse;
  }
}

extern "C" void kernel_launch(void* const* d_in, const int* in_sizes, int n_in,
                              void* d_out, int out_size, void* d_ws, size_t ws_size,
                              hipStream_t stream) {
  const float* x  = (const float*)d_in[0];  // (B,1,28,28) f32
  const float* qp = (const float*)d_in[1];  // (6,) f32
  const float* W  = (const float*)d_in[2];  // (10,784) f32
  const float* bi = (const float*)d_in[3];  // (10,) f32
  float* out = (float*)d_out;               // (B,10) f32

  int Bsz = in_sizes[0] / 784;              // 4096

  int grid = (Bsz + 3) / 4;                 // 1024 blocks, 1 sample per wave
  k_fused<<<grid, 256, 0, stream>>>(x, qp, W, bi, out, Bsz);
}